// Round 6
// baseline (35.151 us; speedup 1.0000x reference)
//
#include <hip/hip_runtime.h>
#include <math.h>

typedef float v2f __attribute__((ext_vector_type(2)));
typedef unsigned long long u64;

constexpr int Gn = 3072;
constexpr int Hn = 5;
constexpr int NQ = 4;            // quarters per batch
constexpr int NBLK = 8;          // 2 batches * 4 quarters
constexpr int QG = Gn / NQ;      // 768
constexpr float EPSf = 1e-6f;
constexpr float L2E  = 1.4426950408889634f;

// ln2^m / m!  m=0..4 (folds 1/m! and exp->exp2 rescale)
__constant__ float INVFL[5] = {
  1.0f, 0.6931471805599453f, 0.2402265069591007f,
  0.05550410866482158f, 0.009618129107628477f };

__device__ __forceinline__ v2f mk2(float a, float b){ v2f r; r.x=a; r.y=b; return r; }
__device__ __forceinline__ v2f pk_mul(v2f a, v2f b){
  v2f d; asm("v_pk_mul_f32 %0, %1, %2" : "=v"(d) : "v"(a), "v"(b)); return d; }
__device__ __forceinline__ v2f pk_add(v2f a, v2f b){
  v2f d; asm("v_pk_add_f32 %0, %1, %2" : "=v"(d) : "v"(a), "v"(b)); return d; }
__device__ __forceinline__ v2f pk_fma(v2f a, v2f b, v2f c){
  v2f d; asm("v_pk_fma_f32 %0, %1, %2, %3" : "=v"(d) : "v"(a), "v"(b), "v"(c)); return d; }

__device__ __forceinline__ float wave_red(float v) {
  int x;
  x = __builtin_amdgcn_update_dpp(0, __float_as_int(v), 0xB1,  0xF, 0xF, true);
  v += __int_as_float(x);
  x = __builtin_amdgcn_update_dpp(0, __float_as_int(v), 0x4E,  0xF, 0xF, true);
  v += __int_as_float(x);
  x = __builtin_amdgcn_update_dpp(0, __float_as_int(v), 0x141, 0xF, 0xF, true);
  v += __int_as_float(x);
  x = __builtin_amdgcn_update_dpp(0, __float_as_int(v), 0x140, 0xF, 0xF, true);
  v += __int_as_float(x);
  v += __shfl_xor(v, 16, 64);
  v += __shfl_xor(v, 32, 64);
  return v;
}

__device__ __forceinline__ u64 pack2(float a, float b) {
  return ((u64)__float_as_uint(b) << 32) | (u64)__float_as_uint(a);
}

// grid barrier: flag-array, per-launch token; replay/poison-safe (see theory)
__device__ __forceinline__ void gbar(u64* flags, int k, int blk, u64 tok, int t) {
  __syncthreads();                            // all block data stores drained
  if (t == 0) {
    __threadfence();                          // agent-scope fence
    __hip_atomic_store(&flags[(k * NBLK + blk) * 8], tok,
                       __ATOMIC_RELEASE, __HIP_MEMORY_SCOPE_AGENT);
  }
  if (t < NBLK) {                             // 8 parallel spinners
    while (__hip_atomic_load(&flags[(k * NBLK + t) * 8],
                             __ATOMIC_ACQUIRE, __HIP_MEMORY_SCOPE_AGENT) != tok)
      __builtin_amdgcn_s_sleep(1);
  }
  __syncthreads();
}

__global__ __launch_bounds__(1024, 4) void net_kernel(
    const float* __restrict__ x,
    const float* __restrict__ WQ1, const float* __restrict__ WK1, const float* __restrict__ WV1,
    const float* __restrict__ WQ2, const float* __restrict__ WK2, const float* __restrict__ WV2,
    const float* __restrict__ WQ3, const float* __restrict__ WK3, const float* __restrict__ WV3,
    const float* __restrict__ W01, const float* __restrict__ W02, const float* __restrict__ W03,
    const float* __restrict__ lna, const float* __restrict__ lnb,
    const float* __restrict__ fcw, const float* __restrict__ fcb,
    float* __restrict__ out, u64* __restrict__ wsu)
{
  __shared__ float hbuf[QG];        // this block's hidden-state quarter
  __shared__ float coeff[Hn * 16];  // [h][0..4]=Z c0..c4, [h][8..12]=F f0..f4
  __shared__ float part[15][9];     // per-wave moment partials
  __shared__ v2f   red2[16];
  __shared__ float lnsc[2];         // mean, inv

  const int t = threadIdx.x;
  const int blk = blockIdx.x;       // 0..7
  const int b = blk >> 2, q = blk & 3;
  const int w = t >> 6, lane = t & 63;

  // ---- workspace layout (u64 units) ----
  u64*   flags = wsu + 8;                                   // 7*8 flags, 64B-padded
  float* mom   = (float*)(wsu + 8 + 7 * NBLK * 8);          // [2][4][48] floats
  u64*   lnst  = (u64*)(mom + 2 * NQ * 48);                 // [2][4] packed (s1,s2)
  u64*   fcst  = lnst + NBLK;                               // [2][4] packed (c0,c1)

  const u64 tok = __hip_atomic_load(wsu, __ATOMIC_ACQUIRE, __HIP_MEMORY_SCOPE_AGENT) + 1;

  const float* WQs[3] = {WQ1, WQ2, WQ3};
  const float* WKs[3] = {WK1, WK2, WK3};
  const float* WVs[3] = {WV1, WV2, WV3};
  const float* W0s[3] = {W01, W02, W03};

  float hv = 0.f, ar = 0.f, br = 0.f;
  if (t < QG) {
    const int gi = q * QG + t;
    hv = x[b * Gn + gi];
    ar = lna[gi];
    br = lnb[gi];
    hbuf[t] = hv;
  }
  __syncthreads();

#pragma unroll
  for (int l = 0; l < 3; ++l) {
    const float* WQ = WQs[l]; const float* WK = WKs[l];
    const float* WV = WVs[l]; const float* W0 = W0s[l];

    // ---- Phase 1: moment partials over this quarter. 15 waves = 5h x 3sub ----
    if (w < 15) {
      const int h = w / 3, sub = w % 3;
      const int jl = sub * 256 + lane * 4;      // local j in quarter
      const float4 xv = *reinterpret_cast<const float4*>(&hbuf[jl]);
      const float4 kk = *reinterpret_cast<const float4*>(&WK[h * Gn + q * QG + jl]);
      const float4 vv = *reinterpret_cast<const float4*>(&WV[h * Gn + q * QG + jl]);

      v2f N1 = mk2(0,0), N2 = N1, N3 = N1, N4 = N1;
      v2f M0 = N1, M1 = N1, M2 = N1, M3 = N1, M4 = N1;
      auto accp = [&](v2f xx, v2f wkv, v2f wvv) {
        v2f k = pk_mul(xx, wkv), v = pk_mul(xx, wvv);
        v2f p2 = pk_mul(k, k), p3 = pk_mul(p2, k), p4 = pk_mul(p2, p2);
        N1 = pk_add(N1, k); N2 = pk_add(N2, p2); N3 = pk_add(N3, p3); N4 = pk_add(N4, p4);
        M0 = pk_add(M0, v);
        M1 = pk_fma(k,  v, M1); M2 = pk_fma(p2, v, M2);
        M3 = pk_fma(p3, v, M3); M4 = pk_fma(p4, v, M4);
      };
      accp(mk2(xv.x, xv.y), mk2(kk.x, kk.y), mk2(vv.x, vv.y));
      accp(mk2(xv.z, xv.w), mk2(kk.z, kk.w), mk2(vv.z, vv.w));

      float r[9];
      r[0] = wave_red(N1.x + N1.y); r[1] = wave_red(N2.x + N2.y);
      r[2] = wave_red(N3.x + N3.y); r[3] = wave_red(N4.x + N4.y);
      r[4] = wave_red(M0.x + M0.y); r[5] = wave_red(M1.x + M1.y);
      r[6] = wave_red(M2.x + M2.y); r[7] = wave_red(M3.x + M3.y);
      r[8] = wave_red(M4.x + M4.y);
      if (lane == 0) {
#pragma unroll
        for (int m = 0; m < 9; ++m) part[w][m] = r[m];
      }
    }

    // ---- Prefetch phase-3 weights (hide HBM/L2 latency under the barrier) ----
    float w0r[Hn], pq[Hn], pkw[Hn], pvw[Hn];
#pragma unroll
    for (int h = 0; h < Hn; ++h) w0r[h] = W0[h];
    if (t < QG) {
      const int gi = q * QG + t;
#pragma unroll
      for (int h = 0; h < Hn; ++h) {
        pq[h]  = WQ[h * Gn + gi];
        pkw[h] = WK[h * Gn + gi];
        pvw[h] = WV[h * Gn + gi];
        asm volatile("" : "+v"(pq[h]), "+v"(pkw[h]), "+v"(pvw[h]));
      }
    }

    __syncthreads();
    // intra-block 3-slice combine -> global moment partials (raw sums)
    if (t < 45) {
      const int h = t / 9, r = t % 9;
      const float s = part[h*3+0][r] + part[h*3+1][r] + part[h*3+2][r];
      __hip_atomic_store(&mom[(b * NQ + q) * 48 + t], s,
                         __ATOMIC_RELEASE, __HIP_MEMORY_SCOPE_AGENT);
    }

    gbar(flags, 2 * l, blk, tok, t);

    // ---- cross-block combine -> coeffs (redundant per block) ----
    if (t < 45) {
      float s = 0.f;
#pragma unroll
      for (int qq = 0; qq < NQ; ++qq)
        s += __hip_atomic_load(&mom[(b * NQ + qq) * 48 + t],
                               __ATOMIC_ACQUIRE, __HIP_MEMORY_SCOPE_AGENT);
      const int h = t / 9, r = t % 9;
      const int m   = (r < 4) ? (r + 1) : (r - 4);
      const int dst = (r < 4) ? (r + 1) : (8 + (r - 4));
      coeff[h * 16 + dst] = s * INVFL[m];
    } else if (t < 50) {
      coeff[(t - 45) * 16] = (float)Gn;   // c0 = N0 = G
    }
    __syncthreads();

    // ---- Phase 3: out_i = (F(qe) - 2^{qe*k} v)/Z(qe); o = sum_h W0_h*out ----
    float o = 0.f;
    if (t < QG) {
#pragma unroll
      for (int h = 0; h < Hn; ++h) {
        const float4 zA = *reinterpret_cast<const float4*>(&coeff[h * 16]);
        const float  z4 = coeff[h * 16 + 4];
        const float4 fA = *reinterpret_cast<const float4*>(&coeff[h * 16 + 8]);
        const float  f4 = coeff[h * 16 + 12];
        const float qe = hv * pq[h] * L2E;
        const float kf = hv * pkw[h];
        const float vf = hv * pvw[h];
        float Z = z4;
        Z = fmaf(Z, qe, zA.w); Z = fmaf(Z, qe, zA.z);
        Z = fmaf(Z, qe, zA.y); Z = fmaf(Z, qe, zA.x);
        float F = f4;
        F = fmaf(F, qe, fA.w); F = fmaf(F, qe, fA.z);
        F = fmaf(F, qe, fA.y); F = fmaf(F, qe, fA.x);
        const float E = __builtin_amdgcn_exp2f(qe * kf);
        o = fmaf(w0r[h], fmaf(-E, vf, F) * __builtin_amdgcn_rcpf(Z), o);
      }
    }

    // ---- LN: block partial stats -> global -> combine -> apply ----
    float s1 = wave_red(o);
    float s2 = wave_red(o * o);
    if (lane == 0) red2[w] = mk2(s1, s2);
    __syncthreads();
    if (t == 0) {
      v2f acc = red2[0];
#pragma unroll
      for (int k = 1; k < 16; ++k) acc = pk_add(acc, red2[k]);
      __hip_atomic_store(&lnst[b * NQ + q], pack2(acc.x, acc.y),
                         __ATOMIC_RELEASE, __HIP_MEMORY_SCOPE_AGENT);
    }

    gbar(flags, 2 * l + 1, blk, tok, t);

    if (t == 0) {
      float a = 0.f, ss = 0.f;
#pragma unroll
      for (int qq = 0; qq < NQ; ++qq) {
        const u64 p = __hip_atomic_load(&lnst[b * NQ + qq],
                                        __ATOMIC_ACQUIRE, __HIP_MEMORY_SCOPE_AGENT);
        a  += __uint_as_float((unsigned)(p & 0xffffffffu));
        ss += __uint_as_float((unsigned)(p >> 32));
      }
      const float mean = a * (1.f / (float)Gn);
      const float var  = fmaxf((ss - a * mean) * (1.f / (float)(Gn - 1)), 0.f);
      lnsc[0] = mean;
      lnsc[1] = __builtin_amdgcn_rcpf(sqrtf(var) + EPSf);
    }
    __syncthreads();
    if (t < QG) {
      hv = hv + ar * (o - lnsc[0]) * lnsc[1] + br;
      hbuf[t] = hv;
    }
    __syncthreads();
  }

  // ---- FC head: per-block partial dots, combine at quarter-0 blocks ----
  float s0 = 0.f, s1 = 0.f;
  if (t < QG) {
    const int gi = q * QG + t;
    s0 = hv * fcw[gi];
    s1 = hv * fcw[Gn + gi];
  }
  s0 = wave_red(s0); s1 = wave_red(s1);
  if (lane == 0) red2[w] = mk2(s0, s1);
  __syncthreads();
  if (t == 0) {
    v2f acc = red2[0];
#pragma unroll
    for (int k = 1; k < 16; ++k) acc = pk_add(acc, red2[k]);
    __hip_atomic_store(&fcst[b * NQ + q], pack2(acc.x, acc.y),
                       __ATOMIC_RELEASE, __HIP_MEMORY_SCOPE_AGENT);
  }

  gbar(flags, 6, blk, tok, t);

  if (q == 0 && t == 0) {
    float a0 = 0.f, a1 = 0.f;
#pragma unroll
    for (int qq = 0; qq < NQ; ++qq) {
      const u64 p = __hip_atomic_load(&fcst[b * NQ + qq],
                                      __ATOMIC_ACQUIRE, __HIP_MEMORY_SCOPE_AGENT);
      a0 += __uint_as_float((unsigned)(p & 0xffffffffu));
      a1 += __uint_as_float((unsigned)(p >> 32));
    }
    out[b * 2 + 0] = a0 + fcb[0];
    out[b * 2 + 1] = a1 + fcb[1];
  }
  // bump epoch for the next (replayed) launch — replay-safe tokens
  if (blk == 0 && t == 0)
    __hip_atomic_store(wsu, tok, __ATOMIC_RELEASE, __HIP_MEMORY_SCOPE_AGENT);
}

extern "C" void kernel_launch(void* const* d_in, const int* in_sizes, int n_in,
                              void* d_out, int out_size, void* d_ws, size_t ws_size,
                              hipStream_t stream) {
  const float* x    = (const float*)d_in[0];
  const float* WQ1  = (const float*)d_in[1];
  const float* WK1  = (const float*)d_in[2];
  const float* WV1  = (const float*)d_in[3];
  const float* WQ2  = (const float*)d_in[4];
  const float* WK2  = (const float*)d_in[5];
  const float* WV2  = (const float*)d_in[6];
  const float* WQ3  = (const float*)d_in[7];
  const float* WK3  = (const float*)d_in[8];
  const float* WV3  = (const float*)d_in[9];
  const float* W01  = (const float*)d_in[10];
  const float* W02  = (const float*)d_in[11];
  const float* W03  = (const float*)d_in[12];
  const float* ln_a = (const float*)d_in[13];
  const float* ln_b = (const float*)d_in[14];
  const float* fc_w = (const float*)d_in[15];
  const float* fc_b = (const float*)d_in[16];

  net_kernel<<<NBLK, 1024, 0, stream>>>(x,
      WQ1, WK1, WV1, WQ2, WK2, WV2, WQ3, WK3, WV3,
      W01, W02, W03, ln_a, ln_b, fc_w, fc_b,
      (float*)d_out, (u64*)d_ws);
}

// Round 7
// 25.652 us; speedup vs baseline: 1.3703x; 1.3703x over previous
//
#include <hip/hip_runtime.h>
#include <math.h>

typedef float v2f __attribute__((ext_vector_type(2)));

constexpr int Gn = 3072;
constexpr int Hn = 5;
constexpr float EPSf = 1e-6f;
constexpr float L2E  = 1.4426950408889634f;

// ln2^m / m!  m=0..4 (folds 1/m! and exp->exp2 rescale into coeffs)
__constant__ float INVFL[5] = {
  1.0f, 0.6931471805599453f, 0.2402265069591007f,
  0.05550410866482158f, 0.009618129107628477f };

struct __align__(16) Smem {
  float hbuf[Gn];         // hidden state (12 KB)
  float coeff[Hn * 16];   // [h][0..4]=Z c0..c4, [h][8..12]=F f0..f4
  float part[15][9];      // per-wave moment partials
  v2f   red2[16];         // LN (s1,s2) per wave
  v2f   red2b[16];        // FC (c0,c1) per wave
};

__device__ __forceinline__ v2f mk2(float a, float b){ v2f r; r.x=a; r.y=b; return r; }
__device__ __forceinline__ v2f pk_mul(v2f a, v2f b){
  v2f d; asm("v_pk_mul_f32 %0, %1, %2" : "=v"(d) : "v"(a), "v"(b)); return d; }
__device__ __forceinline__ v2f pk_add(v2f a, v2f b){
  v2f d; asm("v_pk_add_f32 %0, %1, %2" : "=v"(d) : "v"(a), "v"(b)); return d; }
__device__ __forceinline__ v2f pk_fma(v2f a, v2f b, v2f c){
  v2f d; asm("v_pk_fma_f32 %0, %1, %2, %3" : "=v"(d) : "v"(a), "v"(b), "v"(c)); return d; }

// wave64 sum: 4 DPP steps (VALU only) + 2 shuffles
__device__ __forceinline__ float wave_red(float v) {
  int x;
  x = __builtin_amdgcn_update_dpp(0, __float_as_int(v), 0xB1,  0xF, 0xF, true);
  v += __int_as_float(x);
  x = __builtin_amdgcn_update_dpp(0, __float_as_int(v), 0x4E,  0xF, 0xF, true);
  v += __int_as_float(x);
  x = __builtin_amdgcn_update_dpp(0, __float_as_int(v), 0x141, 0xF, 0xF, true);
  v += __int_as_float(x);
  x = __builtin_amdgcn_update_dpp(0, __float_as_int(v), 0x140, 0xF, 0xF, true);
  v += __int_as_float(x);
  v += __shfl_xor(v, 16, 64);
  v += __shfl_xor(v, 32, 64);
  return v;
}

// depth-4 tree over 16 v2f entries (asm pk_add can't be reassociated -> hand tree)
__device__ __forceinline__ v2f tree16(const v2f* r) {
  v2f a0 = pk_add(r[0], r[8]),  a1 = pk_add(r[1], r[9]);
  v2f a2 = pk_add(r[2], r[10]), a3 = pk_add(r[3], r[11]);
  v2f a4 = pk_add(r[4], r[12]), a5 = pk_add(r[5], r[13]);
  v2f a6 = pk_add(r[6], r[14]), a7 = pk_add(r[7], r[15]);
  a0 = pk_add(a0, a4); a1 = pk_add(a1, a5); a2 = pk_add(a2, a6); a3 = pk_add(a3, a7);
  a0 = pk_add(a0, a2); a1 = pk_add(a1, a3);
  return pk_add(a0, a1);
}

__global__ __launch_bounds__(1024, 4) void net_kernel(
    const float* __restrict__ x,
    const float* __restrict__ WQ1, const float* __restrict__ WK1, const float* __restrict__ WV1,
    const float* __restrict__ WQ2, const float* __restrict__ WK2, const float* __restrict__ WV2,
    const float* __restrict__ WQ3, const float* __restrict__ WK3, const float* __restrict__ WV3,
    const float* __restrict__ W01, const float* __restrict__ W02, const float* __restrict__ W03,
    const float* __restrict__ lna, const float* __restrict__ lnb,
    const float* __restrict__ fcw, const float* __restrict__ fcb,
    float* __restrict__ out)
{
  __shared__ Smem sm;
  const int b = blockIdx.x;
  const int t = threadIdx.x;
  const int w = t >> 6, lane = t & 63;

  const float* WQs[3] = {WQ1, WQ2, WQ3};
  const float* WKs[3] = {WK1, WK2, WK3};
  const float* WVs[3] = {WV1, WV2, WV3};
  const float* W0s[3] = {W01, W02, W03};

  // ---- prologue: x, ln, fc_w all issued at once (cold loads in parallel) ----
  float xx0 = x[b*Gn + t], xx1 = x[b*Gn + t + 1024], xx2 = x[b*Gn + t + 2048];
  const float la0 = lna[t], la1 = lna[t+1024], la2 = lna[t+2048];
  const float lb0 = lnb[t], lb1 = lnb[t+1024], lb2 = lnb[t+2048];
  const float fw00 = fcw[t],      fw01 = fcw[t+1024],      fw02 = fcw[t+2048];
  const float fw10 = fcw[Gn + t], fw11 = fcw[Gn + t+1024], fw12 = fcw[Gn + t+2048];
  sm.hbuf[t] = xx0; sm.hbuf[t+1024] = xx1; sm.hbuf[t+2048] = xx2;
  __syncthreads();

#pragma unroll
  for (int l = 0; l < 3; ++l) {
    const float* WQ = WQs[l]; const float* WK = WKs[l];
    const float* WV = WVs[l]; const float* W0 = W0s[l];

    // ---- Phase 1a: issue + accumulate moments (waves 0..14) ----
    v2f N1 = mk2(0,0), N2 = N1, N3 = N1, N4 = N1;
    v2f M0 = N1, M1 = N1, M2 = N1, M3 = N1, M4 = N1;
    if (w < 15) {
      const int h = w / 3, sl = w % 3;
      const float4* xb4 = reinterpret_cast<const float4*>(sm.hbuf) + sl * 256;
      const float4* wk4 = reinterpret_cast<const float4*>(WK + h * Gn) + sl * 256;
      const float4* wv4 = reinterpret_cast<const float4*>(WV + h * Gn) + sl * 256;
      float4 xv[4], kk[4], vv[4];
#pragma unroll
      for (int it = 0; it < 4; ++it) {
        xv[it] = xb4[it * 64 + lane];
        kk[it] = wk4[it * 64 + lane];
        vv[it] = wv4[it * 64 + lane];
      }
      auto accp = [&](v2f xx, v2f wkv, v2f wvv) {
        v2f k = pk_mul(xx, wkv), v = pk_mul(xx, wvv);
        v2f p2 = pk_mul(k, k), p3 = pk_mul(p2, k), p4 = pk_mul(p2, p2);
        N1 = pk_add(N1, k); N2 = pk_add(N2, p2); N3 = pk_add(N3, p3); N4 = pk_add(N4, p4);
        M0 = pk_add(M0, v);
        M1 = pk_fma(k,  v, M1); M2 = pk_fma(p2, v, M2);
        M3 = pk_fma(p3, v, M3); M4 = pk_fma(p4, v, M4);
      };
#pragma unroll
      for (int it = 0; it < 4; ++it) {
        accp(mk2(xv[it].x, xv[it].y), mk2(kk[it].x, kk[it].y), mk2(vv[it].x, vv[it].y));
        accp(mk2(xv[it].z, xv[it].w), mk2(kk[it].z, kk[it].w), mk2(vv[it].z, vv[it].w));
      }
    }

    // ---- Prefetch ALL phase-3 weights (45 scalars/thread); drain under barriers ----
    float pqA[Hn], pkA[Hn], pvA[Hn];    // rep0 (i = t)
    float pqB[Hn], pkB[Hn], pvB[Hn];    // rep1 (i = t+1024)
    float pqC[Hn], pkC[Hn], pvC[Hn];    // rep2 (i = t+2048)
#pragma unroll
    for (int h = 0; h < Hn; ++h) {
      const float* wq = WQ + h * Gn + t;
      const float* wk = WK + h * Gn + t;
      const float* wv = WV + h * Gn + t;
      pqA[h] = wq[0]; pqB[h] = wq[1024]; pqC[h] = wq[2048];
      pkA[h] = wk[0]; pkB[h] = wk[1024]; pkC[h] = wk[2048];
      pvA[h] = wv[0]; pvB[h] = wv[1024]; pvC[h] = wv[2048];
    }
    float w0r[Hn];
#pragma unroll
    for (int h = 0; h < Hn; ++h) w0r[h] = W0[h];

    // ---- Phase 1b: reduce moments, store partials ----
    if (w < 15) {
      float r[9];
      r[0] = wave_red(N1.x + N1.y); r[1] = wave_red(N2.x + N2.y);
      r[2] = wave_red(N3.x + N3.y); r[3] = wave_red(N4.x + N4.y);
      r[4] = wave_red(M0.x + M0.y); r[5] = wave_red(M1.x + M1.y);
      r[6] = wave_red(M2.x + M2.y); r[7] = wave_red(M3.x + M3.y);
      r[8] = wave_red(M4.x + M4.y);
      if (lane == 0) {
#pragma unroll
        for (int m = 0; m < 9; ++m) sm.part[w][m] = r[m];
      }
    }
    __syncthreads();

    // ---- Phase 2: combine 3 slices, fold ln2^m/m! ----
    if (t < 45) {
      const int h = t / 9, r = t % 9;
      const float s = sm.part[h*3+0][r] + sm.part[h*3+1][r] + sm.part[h*3+2][r];
      const int m   = (r < 4) ? (r + 1) : (r - 4);
      const int dst = (r < 4) ? (r + 1) : (8 + (r - 4));
      sm.coeff[h*16 + dst] = s * INVFL[m];
    } else if (t < 50) {
      sm.coeff[(t - 45) * 16] = (float)Gn;   // c0 = N0 = G
    }
    __syncthreads();

    // ---- Phase 3: all weights already in registers -> pure VALU ----
    v2f o01 = mk2(0.f, 0.f);
    float o2a = 0.f;
#pragma unroll
    for (int h = 0; h < Hn; ++h) {
      const float4 zA = *reinterpret_cast<const float4*>(&sm.coeff[h*16]);
      const float  z4 = sm.coeff[h*16 + 4];
      const float4 fA = *reinterpret_cast<const float4*>(&sm.coeff[h*16 + 8]);
      const float  f4 = sm.coeff[h*16 + 12];
      const float  w0 = w0r[h];

      // packed (rep0, rep1)
      const v2f X  = mk2(xx0, xx1);
      const v2f qe = pk_mul(pk_mul(X, mk2(pqA[h], pqB[h])), mk2(L2E, L2E));
      const v2f kp = pk_mul(X, mk2(pkA[h], pkB[h]));
      const v2f vp = pk_mul(X, mk2(pvA[h], pvB[h]));
      v2f Z = mk2(z4, z4);
      Z = pk_fma(Z, qe, mk2(zA.w, zA.w)); Z = pk_fma(Z, qe, mk2(zA.z, zA.z));
      Z = pk_fma(Z, qe, mk2(zA.y, zA.y)); Z = pk_fma(Z, qe, mk2(zA.x, zA.x));
      v2f F = mk2(f4, f4);
      F = pk_fma(F, qe, mk2(fA.w, fA.w)); F = pk_fma(F, qe, mk2(fA.z, fA.z));
      F = pk_fma(F, qe, mk2(fA.y, fA.y)); F = pk_fma(F, qe, mk2(fA.x, fA.x));
      const v2f qk = pk_mul(qe, kp);
      const float Ex = __builtin_amdgcn_exp2f(qk.x), Ey = __builtin_amdgcn_exp2f(qk.y);
      const float rx = fmaf(-Ex, vp.x, F.x) * __builtin_amdgcn_rcpf(Z.x);
      const float ry = fmaf(-Ey, vp.y, F.y) * __builtin_amdgcn_rcpf(Z.y);
      o01 = pk_fma(mk2(w0, w0), mk2(rx, ry), o01);

      // scalar rep2
      const float qe2 = xx2 * pqC[h] * L2E;
      const float k2  = xx2 * pkC[h];
      const float v2  = xx2 * pvC[h];
      float Zs = z4;
      Zs = fmaf(Zs, qe2, zA.w); Zs = fmaf(Zs, qe2, zA.z);
      Zs = fmaf(Zs, qe2, zA.y); Zs = fmaf(Zs, qe2, zA.x);
      float Fs = f4;
      Fs = fmaf(Fs, qe2, fA.w); Fs = fmaf(Fs, qe2, fA.z);
      Fs = fmaf(Fs, qe2, fA.y); Fs = fmaf(Fs, qe2, fA.x);
      const float Es = __builtin_amdgcn_exp2f(qe2 * k2);
      o2a = fmaf(w0, fmaf(-Es, v2, Fs) * __builtin_amdgcn_rcpf(Zs), o2a);
    }

    // ---- Phase 4: LN stats (one barrier) + residual ----
    float s1 = o01.x + o01.y + o2a;
    float s2 = fmaf(o01.x, o01.x, fmaf(o01.y, o01.y, o2a * o2a));
    s1 = wave_red(s1); s2 = wave_red(s2);
    if (lane == 0) sm.red2[w] = mk2(s1, s2);
    __syncthreads();
    const v2f acc = tree16(sm.red2);
    const float mean = acc.x * (1.f / (float)Gn);
    const float var  = fmaxf((acc.y - acc.x * mean) * (1.f / (float)(Gn - 1)), 0.f);
    const float inv  = __builtin_amdgcn_rcpf(sqrtf(var) + EPSf);
    xx0 = xx0 + la0 * (o01.x - mean) * inv + lb0;
    xx1 = xx1 + la1 * (o01.y - mean) * inv + lb1;
    xx2 = xx2 + la2 * (o2a   - mean) * inv + lb2;
    if (l < 2) {                       // layer 3's h lives in regs only
      sm.hbuf[t]      = xx0;
      sm.hbuf[t+1024] = xx1;
      sm.hbuf[t+2048] = xx2;
      __syncthreads();
    }
  }

  // ---- FC head (weights prefetched in prologue; separate reduce buffer) ----
  v2f sacc = mk2(0.f, 0.f);
  sacc = pk_fma(mk2(xx0, xx0), mk2(fw00, fw10), sacc);
  sacc = pk_fma(mk2(xx1, xx1), mk2(fw01, fw11), sacc);
  sacc = pk_fma(mk2(xx2, xx2), mk2(fw02, fw12), sacc);
  const float s0 = wave_red(sacc.x), s1 = wave_red(sacc.y);
  if (lane == 0) sm.red2b[w] = mk2(s0, s1);
  __syncthreads();
  if (t == 0) {
    const v2f acc = tree16(sm.red2b);
    out[b*2 + 0] = acc.x + fcb[0];
    out[b*2 + 1] = acc.y + fcb[1];
  }
}

extern "C" void kernel_launch(void* const* d_in, const int* in_sizes, int n_in,
                              void* d_out, int out_size, void* d_ws, size_t ws_size,
                              hipStream_t stream) {
  const float* x    = (const float*)d_in[0];
  const float* WQ1  = (const float*)d_in[1];
  const float* WK1  = (const float*)d_in[2];
  const float* WV1  = (const float*)d_in[3];
  const float* WQ2  = (const float*)d_in[4];
  const float* WK2  = (const float*)d_in[5];
  const float* WV2  = (const float*)d_in[6];
  const float* WQ3  = (const float*)d_in[7];
  const float* WK3  = (const float*)d_in[8];
  const float* WV3  = (const float*)d_in[9];
  const float* W01  = (const float*)d_in[10];
  const float* W02  = (const float*)d_in[11];
  const float* W03  = (const float*)d_in[12];
  const float* ln_a = (const float*)d_in[13];
  const float* ln_b = (const float*)d_in[14];
  const float* fc_w = (const float*)d_in[15];
  const float* fc_b = (const float*)d_in[16];

  net_kernel<<<2, 1024, 0, stream>>>(x,
      WQ1, WK1, WV1, WQ2, WK2, WV2, WQ3, WK3, WV3,
      W01, W02, W03, ln_a, ln_b, fc_w, fc_b, (float*)d_out);
}

// Round 10
// 23.909 us; speedup vs baseline: 1.4702x; 1.0729x over previous
//
#include <hip/hip_runtime.h>
#include <math.h>

typedef float v2f __attribute__((ext_vector_type(2)));

constexpr int Gn = 3072;
constexpr int Hn = 5;
constexpr float EPSf = 1e-6f;
constexpr float L2E  = 1.4426950408889634f;
constexpr float Gf   = 3072.0f;

// ln2^m/m! folded at compile time
#define IV1 0.6931471805599453f
#define IV2 0.2402265069591007f
#define IV3 0.05550410866482158f
#define IV4 0.009618129107628477f

struct __align__(16) Smem {
  float hbuf[Gn];        // hidden state (12 KB)
  float part[15 * 16];   // per-wave folded moment partials (lanes 0-8 used)
  float coeffbuf[64];    // combined coeffs, zero-padded to 64
  float s1buf[64];       // LN/FC partial sums, zero-padded
  float s2buf[64];
};

__device__ __forceinline__ v2f mk2(float a, float b){ v2f r; r.x=a; r.y=b; return r; }
__device__ __forceinline__ v2f pk_mul(v2f a, v2f b){
  v2f d; asm("v_pk_mul_f32 %0, %1, %2" : "=v"(d) : "v"(a), "v"(b)); return d; }
__device__ __forceinline__ v2f pk_add(v2f a, v2f b){
  v2f d; asm("v_pk_add_f32 %0, %1, %2" : "=v"(d) : "v"(a), "v"(b)); return d; }
__device__ __forceinline__ v2f pk_fma(v2f a, v2f b, v2f c){
  v2f d; asm("v_pk_fma_f32 %0, %1, %2, %3" : "=v"(d) : "v"(a), "v"(b), "v"(c)); return d; }

// PROVEN (R4-R7): wave64 butterfly sum, result in ALL lanes. 4 DPP + 2 shfl.
__device__ __forceinline__ float wave_red(float v) {
  int x;
  x = __builtin_amdgcn_update_dpp(0, __float_as_int(v), 0xB1,  0xF, 0xF, true); // quad xor1
  v += __int_as_float(x);
  x = __builtin_amdgcn_update_dpp(0, __float_as_int(v), 0x4E,  0xF, 0xF, true); // quad xor2
  v += __int_as_float(x);
  x = __builtin_amdgcn_update_dpp(0, __float_as_int(v), 0x141, 0xF, 0xF, true); // row_half_mirror
  v += __int_as_float(x);
  x = __builtin_amdgcn_update_dpp(0, __float_as_int(v), 0x140, 0xF, 0xF, true); // row_mirror
  v += __int_as_float(x);
  v += __shfl_xor(v, 16, 64);
  v += __shfl_xor(v, 32, 64);
  return v;
}

__device__ __forceinline__ float rlf(float v, int lane){
  return __int_as_float(__builtin_amdgcn_readlane(__float_as_int(v), lane)); }

__global__ __launch_bounds__(1024, 4) void net_kernel(
    const float* __restrict__ x,
    const float* __restrict__ WQ1, const float* __restrict__ WK1, const float* __restrict__ WV1,
    const float* __restrict__ WQ2, const float* __restrict__ WK2, const float* __restrict__ WV2,
    const float* __restrict__ WQ3, const float* __restrict__ WK3, const float* __restrict__ WV3,
    const float* __restrict__ W01, const float* __restrict__ W02, const float* __restrict__ W03,
    const float* __restrict__ lna, const float* __restrict__ lnb,
    const float* __restrict__ fcw, const float* __restrict__ fcb,
    float* __restrict__ out)
{
  __shared__ Smem sm;
  const int b = blockIdx.x;
  const int t = threadIdx.x;
  const int w = t >> 6, lane = t & 63;

  const float* WQs[3] = {WQ1, WQ2, WQ3};
  const float* WKs[3] = {WK1, WK2, WK3};
  const float* WVs[3] = {WV1, WV2, WV3};
  const float* W0s[3] = {W01, W02, W03};

  // ---- prologue ----
  float xx0 = x[b*Gn + t], xx1 = x[b*Gn + t + 1024], xx2 = x[b*Gn + t + 2048];
  const float la0 = lna[t], la1 = lna[t+1024], la2 = lna[t+2048];
  const float lb0 = lnb[t], lb1 = lnb[t+1024], lb2 = lnb[t+2048];
  const float fw00 = fcw[t],      fw01 = fcw[t+1024],      fw02 = fcw[t+2048];
  const float fw10 = fcw[Gn + t], fw11 = fcw[Gn + t+1024], fw12 = fcw[Gn + t+2048];
  sm.hbuf[t] = xx0; sm.hbuf[t+1024] = xx1; sm.hbuf[t+2048] = xx2;
  if (t >= 45 && t < 64) sm.coeffbuf[t] = 0.f;       // pad once; never rewritten
  if (t >= 16 && t < 64) { sm.s1buf[t] = 0.f; sm.s2buf[t] = 0.f; }
  __syncthreads();

#pragma unroll
  for (int l = 0; l < 3; ++l) {
    const float* WQ = WQs[l]; const float* WK = WKs[l];
    const float* WV = WVs[l]; const float* W0 = W0s[l];

    // ---- Phase 1: moments (deg-4), 15 waves = 5 heads x 3 slices ----
    if (w < 15) {
      const int h = w / 3, sl = w % 3;
      const float4* xb4 = reinterpret_cast<const float4*>(sm.hbuf) + sl * 256;
      const float4* wk4 = reinterpret_cast<const float4*>(WK + h * Gn) + sl * 256;
      const float4* wv4 = reinterpret_cast<const float4*>(WV + h * Gn) + sl * 256;
      float4 xv[4], kk[4], vv[4];
#pragma unroll
      for (int it = 0; it < 4; ++it) {
        xv[it] = xb4[it * 64 + lane];
        kk[it] = wk4[it * 64 + lane];
        vv[it] = wv4[it * 64 + lane];
      }
      v2f N1 = mk2(0,0), N2 = N1, N3 = N1, N4 = N1;
      v2f M0 = N1, M1 = N1, M2 = N1, M3 = N1, M4 = N1;
      auto accp = [&](v2f xx, v2f wkv, v2f wvv) {
        v2f k = pk_mul(xx, wkv), v = pk_mul(xx, wvv);
        v2f p2 = pk_mul(k, k), p3 = pk_mul(p2, k), p4 = pk_mul(p2, p2);
        N1 = pk_add(N1, k); N2 = pk_add(N2, p2); N3 = pk_add(N3, p3); N4 = pk_add(N4, p4);
        M0 = pk_add(M0, v);
        M1 = pk_fma(k,  v, M1); M2 = pk_fma(p2, v, M2);
        M3 = pk_fma(p3, v, M3); M4 = pk_fma(p4, v, M4);
      };
#pragma unroll
      for (int it = 0; it < 4; ++it) {
        accp(mk2(xv[it].x, xv[it].y), mk2(kk[it].x, kk[it].y), mk2(vv[it].x, vv[it].y));
        accp(mk2(xv[it].z, xv[it].w), mk2(kk[it].z, kk[it].w), mk2(vv[it].z, vv[it].w));
      }
      // butterfly: ALL lanes hold the sum -> fold 1/m!, pack by lane, 1 ds_write
      const float r0 = wave_red(N1.x + N1.y) * IV1;
      const float r1 = wave_red(N2.x + N2.y) * IV2;
      const float r2 = wave_red(N3.x + N3.y) * IV3;
      const float r3 = wave_red(N4.x + N4.y) * IV4;
      const float r4 = wave_red(M0.x + M0.y);
      const float r5 = wave_red(M1.x + M1.y) * IV1;
      const float r6 = wave_red(M2.x + M2.y) * IV2;
      const float r7 = wave_red(M3.x + M3.y) * IV3;
      const float r8 = wave_red(M4.x + M4.y) * IV4;
      float pv = r0;
      pv = (lane == 1) ? r1 : pv;
      pv = (lane == 2) ? r2 : pv;
      pv = (lane == 3) ? r3 : pv;
      pv = (lane == 4) ? r4 : pv;
      pv = (lane == 5) ? r5 : pv;
      pv = (lane == 6) ? r6 : pv;
      pv = (lane == 7) ? r7 : pv;
      pv = (lane == 8) ? r8 : pv;
      if (lane < 9) sm.part[w * 16 + lane] = pv;
    }

    float w0r[Hn];
#pragma unroll
    for (int h = 0; h < Hn; ++h) w0r[h] = W0[h];   // uniform

    __syncthreads();   // B1: partials visible

    // ---- Phase 2 (wave 0 only): combine 3 slices -> coeffbuf[0..44] ----
    if (t < 45) {
      const int h = t / 9, r = t - 9 * h;
      const int base = h * 48 + r;                  // rows 3h,3h+1,3h+2
      sm.coeffbuf[t] = sm.part[base] + sm.part[base + 16] + sm.part[base + 32];
    }
    __syncthreads();   // B2: coeffs visible

    // ---- Phase 3: 1 non-divergent LDS read/wave; coeffs -> SGPR via readlane ----
    const float cf = sm.coeffbuf[lane];             // zero-padded, all lanes
    float o0 = 0.f, o1 = 0.f, o2 = 0.f;
    const float* wq = WQ + t; const float* wk = WK + t; const float* wv = WV + t;
    float qA = wq[0], qB = wq[1024], qC = wq[2048];
    float kA = wk[0], kB = wk[1024], kC = wk[2048];
    float vA = wv[0], vB = wv[1024], vC = wv[2048];
#pragma unroll
    for (int h = 0; h < Hn; ++h) {
      float nqA, nqB, nqC, nkA, nkB, nkC, nvA, nvB, nvC;
      if (h < Hn - 1) {                              // prefetch next head
        const float* wq2 = WQ + (h+1)*Gn + t;
        const float* wk2 = WK + (h+1)*Gn + t;
        const float* wv2 = WV + (h+1)*Gn + t;
        nqA = wq2[0]; nqB = wq2[1024]; nqC = wq2[2048];
        nkA = wk2[0]; nkB = wk2[1024]; nkC = wk2[2048];
        nvA = wv2[0]; nvB = wv2[1024]; nvC = wv2[2048];
      }
      const float z1 = rlf(cf, h*9+0), z2 = rlf(cf, h*9+1);
      const float z3 = rlf(cf, h*9+2), z4 = rlf(cf, h*9+3);
      const float f0 = rlf(cf, h*9+4), f1 = rlf(cf, h*9+5);
      const float f2 = rlf(cf, h*9+6), f3 = rlf(cf, h*9+7);
      const float f4 = rlf(cf, h*9+8);
      const float w0 = w0r[h];
      auto ev = [&](float xx, float qw, float kw, float vw) -> float {
        const float qe = xx * qw * L2E;
        float Z = z4;
        Z = fmaf(Z, qe, z3); Z = fmaf(Z, qe, z2); Z = fmaf(Z, qe, z1); Z = fmaf(Z, qe, Gf);
        float F = f4;
        F = fmaf(F, qe, f3); F = fmaf(F, qe, f2); F = fmaf(F, qe, f1); F = fmaf(F, qe, f0);
        const float E = __builtin_amdgcn_exp2f(qe * (xx * kw));
        return fmaf(-E, xx * vw, F) * __builtin_amdgcn_rcpf(Z);
      };
      o0 = fmaf(w0, ev(xx0, qA, kA, vA), o0);
      o1 = fmaf(w0, ev(xx1, qB, kB, vB), o1);
      o2 = fmaf(w0, ev(xx2, qC, kC, vC), o2);
      if (h < Hn - 1) {
        qA = nqA; qB = nqB; qC = nqC;
        kA = nkA; kB = nkB; kC = nkC;
        vA = nvA; vB = nvB; vC = nvC;
      }
    }

    // ---- LN: butterfly partials -> padded buf -> butterfly combine ----
    float s1 = o0 + o1 + o2;
    float s2 = fmaf(o0, o0, fmaf(o1, o1, o2 * o2));
    s1 = wave_red(s1); s2 = wave_red(s2);
    if (lane == 0) { sm.s1buf[w] = s1; sm.s2buf[w] = s2; }
    __syncthreads();   // B3: LN partials visible

    const float S1 = wave_red(sm.s1buf[lane]);      // zero-padded -> block sum
    const float S2 = wave_red(sm.s2buf[lane]);
    const float mean = S1 * (1.f / Gf);
    const float var  = fmaxf((S2 - S1 * mean) * (1.f / (Gf - 1.f)), 0.f);
    const float inv  = __builtin_amdgcn_rcpf(sqrtf(var) + EPSf);
    xx0 = xx0 + la0 * (o0 - mean) * inv + lb0;
    xx1 = xx1 + la1 * (o1 - mean) * inv + lb1;
    xx2 = xx2 + la2 * (o2 - mean) * inv + lb2;
    if (l < 2) {
      sm.hbuf[t]      = xx0;
      sm.hbuf[t+1024] = xx1;
      sm.hbuf[t+2048] = xx2;
      __syncthreads(); // B4: next layer reads fresh hbuf
    }
  }

  __syncthreads();     // protect s1buf/s2buf reuse (LN reads done)

  // ---- FC head ----
  float s0 = fmaf(xx0, fw00, fmaf(xx1, fw01, xx2 * fw02));
  float s1 = fmaf(xx0, fw10, fmaf(xx1, fw11, xx2 * fw12));
  s0 = wave_red(s0); s1 = wave_red(s1);
  if (lane == 0) { sm.s1buf[w] = s0; sm.s2buf[w] = s1; }
  __syncthreads();
  if (t == 0) {
    float a0 = 0.f, a1 = 0.f;
#pragma unroll
    for (int k = 0; k < 16; ++k) { a0 += sm.s1buf[k]; a1 += sm.s2buf[k]; }
    out[b*2 + 0] = a0 + fcb[0];
    out[b*2 + 1] = a1 + fcb[1];
  }
}

extern "C" void kernel_launch(void* const* d_in, const int* in_sizes, int n_in,
                              void* d_out, int out_size, void* d_ws, size_t ws_size,
                              hipStream_t stream) {
  const float* x    = (const float*)d_in[0];
  const float* WQ1  = (const float*)d_in[1];
  const float* WK1  = (const float*)d_in[2];
  const float* WV1  = (const float*)d_in[3];
  const float* WQ2  = (const float*)d_in[4];
  const float* WK2  = (const float*)d_in[5];
  const float* WV2  = (const float*)d_in[6];
  const float* WQ3  = (const float*)d_in[7];
  const float* WK3  = (const float*)d_in[8];
  const float* WV3  = (const float*)d_in[9];
  const float* W01  = (const float*)d_in[10];
  const float* W02  = (const float*)d_in[11];
  const float* W03  = (const float*)d_in[12];
  const float* ln_a = (const float*)d_in[13];
  const float* ln_b = (const float*)d_in[14];
  const float* fc_w = (const float*)d_in[15];
  const float* fc_b = (const float*)d_in[16];

  net_kernel<<<2, 1024, 0, stream>>>(x,
      WQ1, WK1, WV1, WQ2, WK2, WV2, WQ3, WK3, WV3,
      W01, W02, W03, ln_a, ln_b, fc_w, fc_b, (float*)d_out);
}